// Round 3
// baseline (221.886 us; speedup 1.0000x reference)
//
#include <hip/hip_runtime.h>
#include <hip/hip_cooperative_groups.h>

namespace cg = cooperative_groups;

// Problem constants
constexpr int cN1 = 85,  cF1 = 256, cO1 = 200, cE1 = 1360;
constexpr int cN2 = 5625, cF2 = 128, cE2 = 180000;

// Workspace layout (4-byte units). First ZERO_WORDS words are zeroed each call.
constexpr int OFF_G1   = 0;          // 17000 f32  (aggregated graph1 output, 85*200)
constexpr int OFF_G2   = 17000;      // 11250 f32  (aggregated graph2 output, 5625*2)
constexpr int OFF_DEG1 = 28250;      // 85    i32  (edge-dst counts, excl. self loop)
constexpr int OFF_DEG2 = 28335;      // 5625  i32
constexpr int ZERO_WORDS = 33960;
constexpr int OFF_H1   = 33960;      // 17000 f32  (x1 @ W1)
constexpr int OFF_H2   = 50960;      // 11250 f32  (x2 @ W2) (even offset -> float2 ok)

constexpr int NBLK = 512, NTHR = 256;
constexpr int GSIZE = NBLK * NTHR;   // 131072 threads

__global__ __launch_bounds__(NTHR, 2) void fused_gcn(
    const float* __restrict__ x1, const float* __restrict__ x2,
    const float* __restrict__ W1, const float* __restrict__ b1,
    const float* __restrict__ W2, const float* __restrict__ b2,
    const float* __restrict__ Wf, const float* __restrict__ bf,
    const int* __restrict__ ei1, const int* __restrict__ ei2,
    float* __restrict__ ws_f, float* __restrict__ out)
{
    cg::grid_group grid = cg::this_grid();
    int* ws_i = reinterpret_cast<int*>(ws_f);
    const int b = blockIdx.x, t = threadIdx.x;
    const int gtid = b * NTHR + t;

    // ---------------- P0: zero accumulators + both GEMMs (independent) ----------
    for (int i = gtid; i < ZERO_WORDS; i += GSIZE) ws_f[i] = 0.f;

    // GEMM1: block b (<85) computes h1[b][t] for t<200
    if (b < cN1 && t < cO1) {
        const float* xr = x1 + b * cF1;              // uniform across block
        float s = 0.f;
        #pragma unroll 8
        for (int k = 0; k < cF1; ++k)
            s = fmaf(xr[k], W1[k * cO1 + t], s);     // coalesced across t
        ws_f[OFF_H1 + b * cO1 + t] = s;
    }

    // GEMM2: one 32-lane group per row (W2 is 1 KB -> L1-resident)
    {
        int g = gtid >> 5, l = t & 31, ng = GSIZE >> 5;   // 4096 groups
        for (int row = g; row < cN2; row += ng) {
            float4 xv = reinterpret_cast<const float4*>(x2 + row * cF2)[l];
            int kb = l * 4;
            float p0 = xv.x * W2[(kb + 0) * 2 + 0] + xv.y * W2[(kb + 1) * 2 + 0]
                     + xv.z * W2[(kb + 2) * 2 + 0] + xv.w * W2[(kb + 3) * 2 + 0];
            float p1 = xv.x * W2[(kb + 0) * 2 + 1] + xv.y * W2[(kb + 1) * 2 + 1]
                     + xv.z * W2[(kb + 2) * 2 + 1] + xv.w * W2[(kb + 3) * 2 + 1];
            #pragma unroll
            for (int m = 16; m >= 1; m >>= 1) {
                p0 += __shfl_xor(p0, m);
                p1 += __shfl_xor(p1, m);
            }
            if (l == 0) {
                ws_f[OFF_H2 + row * 2 + 0] = p0;
                ws_f[OFF_H2 + row * 2 + 1] = p1;
            }
        }
    }

    grid.sync();

    // ---------------- P1: degree histogram over real-edge dst ------------------
    for (int i = gtid; i < cE1 + cE2; i += GSIZE) {
        if (i < cE1) atomicAdd(&ws_i[OFF_DEG1 + ei1[cE1 + i]], 1);
        else         atomicAdd(&ws_i[OFF_DEG2 + ei2[cE2 + (i - cE1)]], 1);
    }

    grid.sync();

    // ---------------- P2: normalized scatter-add (incl. self loops) ------------
    // graph1: one block per edge-unit, 200 lanes wide
    for (int u = b; u < cE1 + cN1; u += NBLK) {
        int src, dst;
        if (u < cE1) { src = ei1[u]; dst = ei1[cE1 + u]; }
        else         { src = dst = u - cE1; }                       // self loop
        float norm = rsqrtf((float)(ws_i[OFF_DEG1 + src] + 1))
                   * rsqrtf((float)(ws_i[OFF_DEG1 + dst] + 1));
        if (t < cO1)
            atomicAdd(&ws_f[OFF_G1 + dst * cO1 + t],
                      ws_f[OFF_H1 + src * cO1 + t] * norm);
    }
    // graph2: one thread per edge-unit
    for (int e = gtid; e < cE2 + cN2; e += GSIZE) {
        int src, dst;
        if (e < cE2) { src = ei2[e]; dst = ei2[cE2 + e]; }
        else         { src = dst = e - cE2; }                       // self loop
        float norm = rsqrtf((float)(ws_i[OFF_DEG2 + src] + 1))
                   * rsqrtf((float)(ws_i[OFF_DEG2 + dst] + 1));
        float2 h = reinterpret_cast<const float2*>(ws_f + OFF_H2)[src];
        atomicAdd(&ws_f[OFF_G2 + dst * 2 + 0], h.x * norm);
        atomicAdd(&ws_f[OFF_G2 + dst * 2 + 1], h.y * norm);
    }

    grid.sync();

    // ---------------- P3: bias + reshape/concat + relu + final linear ----------
    __shared__ float sh[113];
    if (b < 250) {
        if (t < 113) {
            float v;
            if (t < 68) { int f = b * 68 + t;        v = ws_f[OFF_G1 + f] + b1[f % 200]; }
            else        { int f = b * 45 + (t - 68); v = ws_f[OFF_G2 + f] + b2[f & 1];  }
            sh[t] = fmaxf(v, 0.f);
        }
        __syncthreads();
        if (t < 5) {
            float s = bf[t];
            #pragma unroll 1
            for (int k = 0; k < 113; ++k)
                s = fmaf(sh[k], Wf[k * 5 + t], s);
            out[b * 5 + t] = s;
        }
    }
}

extern "C" void kernel_launch(void* const* d_in, const int* in_sizes, int n_in,
                              void* d_out, int out_size, void* d_ws, size_t ws_size,
                              hipStream_t stream)
{
    const float* x1 = (const float*)d_in[0];
    const float* x2 = (const float*)d_in[1];
    const float* W1 = (const float*)d_in[2];
    const float* b1 = (const float*)d_in[3];
    const float* W2 = (const float*)d_in[4];
    const float* b2 = (const float*)d_in[5];
    const float* Wf = (const float*)d_in[6];
    const float* bf = (const float*)d_in[7];
    const int*   ei1 = (const int*)d_in[8];
    const int*   ei2 = (const int*)d_in[9];
    float* ws_f = (float*)d_ws;
    float* out  = (float*)d_out;

    void* args[] = {
        (void*)&x1, (void*)&x2, (void*)&W1, (void*)&b1, (void*)&W2, (void*)&b2,
        (void*)&Wf, (void*)&bf, (void*)&ei1, (void*)&ei2, (void*)&ws_f, (void*)&out
    };
    hipLaunchCooperativeKernel((const void*)fused_gcn, dim3(NBLK), dim3(NTHR),
                               args, 0, stream);
}

// Round 4
// 105.792 us; speedup vs baseline: 2.0974x; 2.0974x over previous
//
#include <hip/hip_runtime.h>

// Problem constants
constexpr int cN1 = 85,  cF1 = 256, cO1 = 200, cE1 = 1360;
constexpr int cN2 = 5625, cF2 = 128, cE2 = 180000;

// Workspace layout (4-byte units). [0, ZERO_WORDS) zeroed by k_init each call.
constexpr int OFF_G1   = 0;          // 17000 f32 (aggregated graph1 out, 85*200)
constexpr int OFF_G2   = 17000;      // 11250 f32 (aggregated graph2 out, 5625*2)
constexpr int OFF_DEG1 = 28250;      // 85    i32
constexpr int OFF_DEG2 = 28335;      // 5625  i32
constexpr int OFF_BAR  = 33960;      // 3 barriers * (32 leaf + 1 root) + 1 release
constexpr int ZERO_WORDS = 34060;
constexpr int OFF_H1   = 34060;      // 17000 f32 (x1 @ W1)
constexpr int OFF_H2   = 51060;      // 11250 f32 (x2 @ W2) (even -> float2 ok)

constexpr int NBLK = 512, NTHR = 256;
constexpr int GSIZE = NBLK * NTHR;

// ---------------- init: zero accumulators, degrees, barrier state ----------------
__global__ __launch_bounds__(256) void k_init(float* __restrict__ ws_f)
{
    int i = blockIdx.x * 256 + threadIdx.x;
    if (i < ZERO_WORDS) ws_f[i] = 0.f;
}

// ---------------- fast two-level grid barrier (all 512 blocks co-resident) ------
// leaf j (j = b&31) collects 16 arrivals -> root collects 32 -> release = bi+1.
__device__ __forceinline__ void grid_barrier(int* ws_i, int bi)
{
    __syncthreads();
    if (threadIdx.x == 0) {
        __threadfence();                                  // publish my writes
        int* L = ws_i + OFF_BAR + bi * 33;
        int* rel = ws_i + OFF_BAR + 99;
        if (atomicAdd(&L[blockIdx.x & 31], 1) == 15) {
            if (atomicAdd(&L[32], 1) == 31) {
                __threadfence();
                atomicExch(rel, bi + 1);                  // release
            }
        }
        while (__hip_atomic_load(rel, __ATOMIC_RELAXED,
                                 __HIP_MEMORY_SCOPE_AGENT) < bi + 1)
            __builtin_amdgcn_s_sleep(2);
        __threadfence();                                  // acquire
    }
    __syncthreads();
}

__global__ __launch_bounds__(NTHR, 2) void fused_gcn(
    const float* __restrict__ x1, const float* __restrict__ x2,
    const float* __restrict__ W1, const float* __restrict__ b1,
    const float* __restrict__ W2, const float* __restrict__ b2,
    const float* __restrict__ Wf, const float* __restrict__ bf,
    const int* __restrict__ ei1, const int* __restrict__ ei2,
    float* __restrict__ ws_f, float* __restrict__ out)
{
    int* ws_i = reinterpret_cast<int*>(ws_f);
    const int b = blockIdx.x, t = threadIdx.x;
    const int gtid = b * NTHR + t;

    // ---------------- P0: both GEMMs (independent of everything) ----------------
    // GEMM1: block b (<85) computes h1[b][t] for t<200
    if (b < cN1 && t < cO1) {
        const float* xr = x1 + b * cF1;              // uniform across block
        float s = 0.f;
        #pragma unroll 8
        for (int k = 0; k < cF1; ++k)
            s = fmaf(xr[k], W1[k * cO1 + t], s);     // coalesced across t
        ws_f[OFF_H1 + b * cO1 + t] = s;
    }

    // GEMM2: one 32-lane group per row (W2 is 1 KB -> cache-resident)
    {
        int g = gtid >> 5, l = t & 31, ng = GSIZE >> 5;   // 4096 groups
        for (int row = g; row < cN2; row += ng) {
            float4 xv = reinterpret_cast<const float4*>(x2 + row * cF2)[l];
            int kb = l * 4;
            float p0 = xv.x * W2[(kb + 0) * 2 + 0] + xv.y * W2[(kb + 1) * 2 + 0]
                     + xv.z * W2[(kb + 2) * 2 + 0] + xv.w * W2[(kb + 3) * 2 + 0];
            float p1 = xv.x * W2[(kb + 0) * 2 + 1] + xv.y * W2[(kb + 1) * 2 + 1]
                     + xv.z * W2[(kb + 2) * 2 + 1] + xv.w * W2[(kb + 3) * 2 + 1];
            #pragma unroll
            for (int m = 16; m >= 1; m >>= 1) {
                p0 += __shfl_xor(p0, m);
                p1 += __shfl_xor(p1, m);
            }
            if (l == 0) {
                ws_f[OFF_H2 + row * 2 + 0] = p0;
                ws_f[OFF_H2 + row * 2 + 1] = p1;
            }
        }
    }

    // P1 (concurrent with P0 tail): degree histogram over real-edge dst
    for (int i = gtid; i < cE1 + cE2; i += GSIZE) {
        if (i < cE1) atomicAdd(&ws_i[OFF_DEG1 + ei1[cE1 + i]], 1);
        else         atomicAdd(&ws_i[OFF_DEG2 + ei2[cE2 + (i - cE1)]], 1);
    }

    grid_barrier(ws_i, 0);   // degrees + h1/h2 final

    // ---------------- P2: normalized scatter-add (incl. self loops) ------------
    // graph1: one block per edge-unit, 200 lanes wide
    for (int u = b; u < cE1 + cN1; u += NBLK) {
        int src, dst;
        if (u < cE1) { src = ei1[u]; dst = ei1[cE1 + u]; }
        else         { src = dst = u - cE1; }                       // self loop
        float norm = rsqrtf((float)(ws_i[OFF_DEG1 + src] + 1))
                   * rsqrtf((float)(ws_i[OFF_DEG1 + dst] + 1));
        if (t < cO1)
            atomicAdd(&ws_f[OFF_G1 + dst * cO1 + t],
                      ws_f[OFF_H1 + src * cO1 + t] * norm);
    }
    // graph2: one thread per edge-unit
    for (int e = gtid; e < cE2 + cN2; e += GSIZE) {
        int src, dst;
        if (e < cE2) { src = ei2[e]; dst = ei2[cE2 + e]; }
        else         { src = dst = e - cE2; }                       // self loop
        float norm = rsqrtf((float)(ws_i[OFF_DEG2 + src] + 1))
                   * rsqrtf((float)(ws_i[OFF_DEG2 + dst] + 1));
        float2 h = reinterpret_cast<const float2*>(ws_f + OFF_H2)[src];
        atomicAdd(&ws_f[OFF_G2 + dst * 2 + 0], h.x * norm);
        atomicAdd(&ws_f[OFF_G2 + dst * 2 + 1], h.y * norm);
    }

    grid_barrier(ws_i, 1);   // aggregation final

    // ---------------- P3: bias + reshape/concat + relu + final linear ----------
    __shared__ float sh[113];
    if (b < 250) {
        if (t < 113) {
            float v;
            if (t < 68) { int f = b * 68 + t;        v = ws_f[OFF_G1 + f] + b1[f % 200]; }
            else        { int f = b * 45 + (t - 68); v = ws_f[OFF_G2 + f] + b2[f & 1];  }
            sh[t] = fmaxf(v, 0.f);
        }
        __syncthreads();
        if (t < 5) {
            float s = bf[t];
            #pragma unroll 1
            for (int k = 0; k < 113; ++k)
                s = fmaf(sh[k], Wf[k * 5 + t], s);
            out[b * 5 + t] = s;
        }
    }
}

extern "C" void kernel_launch(void* const* d_in, const int* in_sizes, int n_in,
                              void* d_out, int out_size, void* d_ws, size_t ws_size,
                              hipStream_t stream)
{
    const float* x1 = (const float*)d_in[0];
    const float* x2 = (const float*)d_in[1];
    const float* W1 = (const float*)d_in[2];
    const float* b1 = (const float*)d_in[3];
    const float* W2 = (const float*)d_in[4];
    const float* b2 = (const float*)d_in[5];
    const float* Wf = (const float*)d_in[6];
    const float* bf = (const float*)d_in[7];
    const int*   ei1 = (const int*)d_in[8];
    const int*   ei2 = (const int*)d_in[9];
    float* ws_f = (float*)d_ws;
    float* out  = (float*)d_out;

    k_init<<<(ZERO_WORDS + 255) / 256, 256, 0, stream>>>(ws_f);

    void* args[] = {
        (void*)&x1, (void*)&x2, (void*)&W1, (void*)&b1, (void*)&W2, (void*)&b2,
        (void*)&Wf, (void*)&bf, (void*)&ei1, (void*)&ei2, (void*)&ws_f, (void*)&out
    };
    hipLaunchCooperativeKernel((const void*)fused_gcn, dim3(NBLK), dim3(NTHR),
                               args, 0, stream);
}

// Round 6
// 80.989 us; speedup vs baseline: 2.7397x; 1.3062x over previous
//
#include <hip/hip_runtime.h>

// Problem constants
constexpr int cN1 = 85,  cF1 = 256, cO1 = 200, cE1 = 1360;
constexpr int cN2 = 5625, cF2 = 128, cE2 = 180000;

// Workspace layout (4-byte words), parameterized by `pad`:
//   off_g2p   = 0          : cN2*pad f32  (node n comps at n*pad+0 / +1)  [zeroed]
//   off_deg2p = cN2*pad    : cN2*pad i32                                  [zeroed]
//   zw        = 2*cN2*pad  (zero extent)
//   off_g1    = zw         : 17000 f32  (graph1 aggregated out; plain-written)
//   off_h1    =  +17000    : 17000 f32  (x1 @ W1)
//   off_h2    =  +17000    : 11250 f32  (x2 @ W2; even offset -> float2 ok)
__host__ __device__ inline void layout(int pad, int& zw, int& off_deg2p,
                                       int& off_g1, int& off_h1, int& off_h2,
                                       int& end)
{
    off_deg2p = cN2 * pad;
    zw        = 2 * cN2 * pad;
    off_g1    = zw;
    off_h1    = off_g1 + cN1 * cO1;
    off_h2    = off_h1 + cN1 * cO1;
    end       = off_h2 + cN2 * 2;
}

// ---------------- K1: zero atomic targets + both GEMMs (role-split grid) --------
// blocks [0,85): GEMM1 | [85,789): GEMM2 (8 rows each) | [789,789+ZB): zero
constexpr int K1_G2B = (cN2 + 7) / 8;          // 704
__global__ __launch_bounds__(256) void k1_gemm_zero(
    const float* __restrict__ x1, const float* __restrict__ x2,
    const float* __restrict__ W1, const float* __restrict__ W2,
    float* __restrict__ ws_f, int pad, int zb)
{
    int zw, off_deg2p, off_g1, off_h1, off_h2, end;
    layout(pad, zw, off_deg2p, off_g1, off_h1, off_h2, end);
    int b = blockIdx.x, t = threadIdx.x;

    if (b < cN1) {
        // GEMM1: h1[b][t] = sum_k x1[b][k] * W1[k][t]  (t < 200)
        if (t < cO1) {
            const float* xr = x1 + b * cF1;              // uniform across block
            float s = 0.f;
            #pragma unroll 8
            for (int k = 0; k < cF1; ++k)
                s = fmaf(xr[k], W1[k * cO1 + t], s);     // coalesced across t
            ws_f[off_h1 + b * cO1 + t] = s;
        }
        return;
    }
    b -= cN1;

    if (b < K1_G2B) {
        // GEMM2: 32-lane group per row; W2 (1 KB) stays cache-resident.
        int row = b * 8 + (t >> 5), l = t & 31;
        if (row < cN2) {
            float4 xv = reinterpret_cast<const float4*>(x2 + row * cF2)[l];
            int kb = l * 4;
            float p0 = xv.x * W2[(kb + 0) * 2 + 0] + xv.y * W2[(kb + 1) * 2 + 0]
                     + xv.z * W2[(kb + 2) * 2 + 0] + xv.w * W2[(kb + 3) * 2 + 0];
            float p1 = xv.x * W2[(kb + 0) * 2 + 1] + xv.y * W2[(kb + 1) * 2 + 1]
                     + xv.z * W2[(kb + 2) * 2 + 1] + xv.w * W2[(kb + 3) * 2 + 1];
            #pragma unroll
            for (int m = 16; m >= 1; m >>= 1) {
                p0 += __shfl_xor(p0, m);
                p1 += __shfl_xor(p1, m);
            }
            if (l == 0) {
                ws_f[off_h2 + row * 2 + 0] = p0;
                ws_f[off_h2 + row * 2 + 1] = p1;
            }
        }
        return;
    }
    b -= K1_G2B;

    // zero role: grid-stride over [0, zw)
    for (int i = b * 256 + t; i < zw; i += zb * 256) ws_f[i] = 0.f;
}

// ---------------- K2: graph1 aggregation (self-contained) + deg2 histogram ------
// blocks [0,85): one per graph1 node | [85, 85+704): deg2 histogram
constexpr int K2_DEGB = (cE2 + 255) / 256;     // 704
__global__ __launch_bounds__(256) void k2_g1agg_deg2(
    const int* __restrict__ ei1, const int* __restrict__ ei2,
    float* __restrict__ ws_f, int pad)
{
    int zw, off_deg2p, off_g1, off_h1, off_h2, end;
    layout(pad, zw, off_deg2p, off_g1, off_h1, off_h2, end);
    int* ws_i = reinterpret_cast<int*>(ws_f);
    int b = blockIdx.x, t = threadIdx.x;

    if (b < cN1) {
        __shared__ int   s_src[cE1];
        __shared__ int   s_dst[cE1];
        __shared__ int   s_deg[cN1];
        __shared__ float s_acc[cO1];
        for (int i = t; i < cE1; i += 256) { s_src[i] = ei1[i]; s_dst[i] = ei1[cE1 + i]; }
        if (t < cN1) s_deg[t] = 0;
        for (int i = t; i < cO1; i += 256) s_acc[i] = 0.f;
        __syncthreads();
        for (int i = t; i < cE1; i += 256) atomicAdd(&s_deg[s_dst[i]], 1);
        __syncthreads();
        // gather: 4 waves split the edge list; lanes split the 200 features
        int w = t >> 6, lane = t & 63;
        int e0 = w * (cE1 / 4), e1 = e0 + (cE1 / 4);       // 340 edges / wave
        for (int e = e0; e < e1; ++e) {
            if (s_dst[e] == b) {
                int src = s_src[e];
                float dsv = rsqrtf((float)(s_deg[src] + 1));
                const float* hrow = ws_f + off_h1 + src * cO1;
                for (int f = lane; f < cO1; f += 64)
                    atomicAdd(&s_acc[f], hrow[f] * dsv);   // LDS atomic, sparse
            }
        }
        __syncthreads();
        float dn = rsqrtf((float)(s_deg[b] + 1));
        for (int i = t; i < cO1; i += 256)
            ws_f[off_g1 + b * cO1 + i] =
                dn * (s_acc[i] + dn * ws_f[off_h1 + b * cO1 + i]);
        return;
    }
    b -= cN1;

    // deg2 histogram over real-edge dst (padded counters -> channel spread)
    int e = b * 256 + t;
    if (e < cE2) atomicAdd(&ws_i[off_deg2p + ei2[cE2 + e] * pad], 1);
}

// ---------------- K3: graph2 scatter (padded f32 atomics, incl. self loops) -----
constexpr int K3_GRID = (cE2 + cN2 + 255) / 256;   // 726
__global__ __launch_bounds__(256) void k3_scatter2(
    const int* __restrict__ ei2, float* __restrict__ ws_f, int pad)
{
    int zw, off_deg2p, off_g1, off_h1, off_h2, end;
    layout(pad, zw, off_deg2p, off_g1, off_h1, off_h2, end);
    int* ws_i = reinterpret_cast<int*>(ws_f);
    int e = blockIdx.x * 256 + threadIdx.x;
    if (e >= cE2 + cN2) return;
    int src, dst;
    if (e < cE2) { src = ei2[e]; dst = ei2[cE2 + e]; }
    else         { src = dst = e - cE2; }                       // self loop
    float norm = rsqrtf((float)(ws_i[off_deg2p + src * pad] + 1))
               * rsqrtf((float)(ws_i[off_deg2p + dst * pad] + 1));
    float2 h = reinterpret_cast<const float2*>(ws_f + off_h2)[src];
    atomicAdd(&ws_f[dst * pad + 0], h.x * norm);
    atomicAdd(&ws_f[dst * pad + 1], h.y * norm);
}

// ---------------- K4: bias + reshape/concat + relu + final linear ---------------
__global__ __launch_bounds__(128) void k4_head(
    const float* __restrict__ ws_f,
    const float* __restrict__ b1, const float* __restrict__ b2,
    const float* __restrict__ Wf, const float* __restrict__ bf,
    float* __restrict__ out, int pad)
{
    int zw, off_deg2p, off_g1, off_h1, off_h2, end;
    layout(pad, zw, off_deg2p, off_g1, off_h1, off_h2, end);
    __shared__ float sh[113];
    int r = blockIdx.x, t = threadIdx.x;
    if (t < 113) {
        float v;
        if (t < 68) {
            int f = r * 68 + t;                       // h1 reshape(250,68) flat
            v = ws_f[off_g1 + f] + b1[f % 200];
        } else {
            int f = r * 45 + (t - 68);                // h2 reshape(250,45) flat
            v = ws_f[(f >> 1) * pad + (f & 1)] + b2[f & 1];
        }
        sh[t] = fmaxf(v, 0.f);
    }
    __syncthreads();
    if (t < 5) {
        float s = bf[t];
        #pragma unroll 1
        for (int k = 0; k < 113; ++k)
            s = fmaf(sh[k], Wf[k * 5 + t], s);
        out[r * 5 + t] = s;
    }
}

extern "C" void kernel_launch(void* const* d_in, const int* in_sizes, int n_in,
                              void* d_out, int out_size, void* d_ws, size_t ws_size,
                              hipStream_t stream)
{
    const float* x1 = (const float*)d_in[0];
    const float* x2 = (const float*)d_in[1];
    const float* W1 = (const float*)d_in[2];
    const float* b1 = (const float*)d_in[3];
    const float* W2 = (const float*)d_in[4];
    const float* b2 = (const float*)d_in[5];
    const float* Wf = (const float*)d_in[6];
    const float* bf = (const float*)d_in[7];
    const int*   ei1 = (const int*)d_in[8];
    const int*   ei2 = (const int*)d_in[9];
    float* ws_f = (float*)d_ws;
    float* out  = (float*)d_out;

    // Largest padding that fits the workspace (pad words per atomic counter).
    int pad = 1;
    for (int cand : {64, 8, 1}) {
        int zw, od2, og1, oh1, oh2, end;
        layout(cand, zw, od2, og1, oh1, oh2, end);
        if ((size_t)end * 4 <= ws_size) { pad = cand; break; }
    }
    int zw, od2, og1, oh1, oh2, end;
    layout(pad, zw, od2, og1, oh1, oh2, end);
    int zb = (zw + 1023) / 1024;                       // zero-role blocks (4 it/thr)

    k1_gemm_zero<<<cN1 + K1_G2B + zb, 256, 0, stream>>>(x1, x2, W1, W2, ws_f, pad, zb);
    k2_g1agg_deg2<<<cN1 + K2_DEGB, 256, 0, stream>>>(ei1, ei2, ws_f, pad);
    k3_scatter2<<<K3_GRID, 256, 0, stream>>>(ei2, ws_f, pad);
    k4_head<<<250, 128, 0, stream>>>(ws_f, b1, b2, Wf, bf, out, pad);
}